// Round 6
// baseline (202.989 us; speedup 1.0000x reference)
//
#include <hip/hip_runtime.h>

#define B_    16
#define L_    1024
#define H_    8
#define SCALE  0.17677669529663687f              // 1/sqrt(32)
#define QSCALE 0.25510940349191965f              // SCALE * log2(e)  (exp -> exp2)

typedef __attribute__((ext_vector_type(8))) short bf16x8;
typedef __attribute__((ext_vector_type(4))) float f32x4;
typedef unsigned short u16t;

__device__ inline u16t f2bf(float f) {
    unsigned u = __float_as_uint(f);
    u = (u + 0x7FFF + ((u >> 16) & 1)) >> 16;
    return (u16t)u;
}
__device__ inline unsigned f2bf_pk(float a, float b) {
    unsigned ua = __float_as_uint(a);
    unsigned ub = __float_as_uint(b);
    ua = (ua + 0x7FFF + ((ua >> 16) & 1)) >> 16;
    ub = (ub + 0x7FFF + ((ub >> 16) & 1)) >> 16;
    return ua | (ub << 16);
}
__device__ inline uint2 f2bf_pk4(float a, float b, float c, float d) {
    uint2 u; u.x = f2bf_pk(a, b); u.y = f2bf_pk(c, d); return u;
}
// truncating bf16 pack: low16 = hi(f0), high16 = hi(f1) — one v_perm_b32
__device__ inline unsigned trunc_pk(float f0, float f1) {
    return __builtin_amdgcn_perm(__float_as_uint(f1), __float_as_uint(f0), 0x07060302u);
}

// ---------------------------------------------------------------------------
// Prep: z=0 -> transpose+convert x (B,128,1024) fp32 -> xbT (B,1024,128) bf16
//       z=1 -> convert the three weight matrices fp32 -> bf16 (flat copy)
// ---------------------------------------------------------------------------
__global__ __launch_bounds__(256) void prep_kernel(
    const float* __restrict__ x, const float* __restrict__ w_qkv,
    const float* __restrict__ w_o, const float* __restrict__ w_res,
    u16t* __restrict__ xbT, u16t* __restrict__ wqb,
    u16t* __restrict__ wob, u16t* __restrict__ wrb)
{
    const int tid = threadIdx.x;
    if (blockIdx.z == 0) {
        __shared__ u16t T[64][144];
        const int b = blockIdx.y, l0 = blockIdx.x * 64;
#pragma unroll
        for (int i = 0; i < 8; i++) {
            const int c = i * 16 + (tid >> 4);
            const int l = (tid & 15) * 4;
            const float4 v = *(const float4*)(x + ((long)b * 128 + c) * 1024 + l0 + l);
            T[l + 0][c] = f2bf(v.x);
            T[l + 1][c] = f2bf(v.y);
            T[l + 2][c] = f2bf(v.z);
            T[l + 3][c] = f2bf(v.w);
        }
        __syncthreads();
#pragma unroll
        for (int i = 0; i < 4; i++) {
            const int l  = i * 16 + (tid >> 4);
            const int c0 = (tid & 15) * 8;
            *(uint4*)(xbT + ((long)b * 1024 + l0 + l) * 128 + c0) = *(const uint4*)&T[l][c0];
        }
    } else {
        const int idx = blockIdx.y * 16 + blockIdx.x;
        if (idx >= 144) return;
        const int f = idx * 1024 + tid * 4;
        const float* src; u16t* dst; int off;
        if (f < 98304)       { src = w_qkv; dst = wqb; off = f; }
        else if (f < 131072) { src = w_o;   dst = wob; off = f - 98304; }
        else                 { src = w_res; dst = wrb; off = f - 131072; }
        const float4 v = *(const float4*)(src + off);
        *(uint2*)(dst + off) = f2bf_pk4(v.x, v.y, v.z, v.w);
    }
}

// ---------------------------------------------------------------------------
// QKV GEMM: block = (lblk 128, bh). Wave: 96 o x 32 l, K=128 (4 unrolled
// steps, 12 independent MFMAs each). Q folds QSCALE; Q,K transposed; V natural.
// ---------------------------------------------------------------------------
__global__ __launch_bounds__(256) void qkv_gemm_kernel(
    const u16t* __restrict__ wqb, const u16t* __restrict__ xbT,
    const float* __restrict__ b_qkv,
    u16t* __restrict__ qT, u16t* __restrict__ kT, u16t* __restrict__ vN)
{
    const int lblk = blockIdx.x * 128;
    const int bh = blockIdx.y;
    const int b = bh >> 3, h = bh & 7;
    const int tid = threadIdx.x, lane = tid & 63, wv = tid >> 6;
    const int l15 = lane & 15, quad = lane >> 4;
    const int lw = lblk + wv * 32;

    f32x4 acc[6][2];
#pragma unroll
    for (int mi = 0; mi < 6; mi++)
#pragma unroll
        for (int ni = 0; ni < 2; ni++) acc[mi][ni] = (f32x4)0.f;

    const u16t* wrow = wqb + (long)h * 96 * 128;
#pragma unroll
    for (int ks = 0; ks < 4; ks++) {
        const int k0 = ks * 32 + quad * 8;
        bf16x8 af[6], bf[2];
#pragma unroll
        for (int mi = 0; mi < 6; mi++)
            af[mi] = *(const bf16x8*)(wrow + (mi * 16 + l15) * 128 + k0);
#pragma unroll
        for (int ni = 0; ni < 2; ni++)
            bf[ni] = *(const bf16x8*)(xbT + ((long)b * 1024 + lw + ni * 16 + l15) * 128 + k0);
#pragma unroll
        for (int mi = 0; mi < 6; mi++)
#pragma unroll
            for (int ni = 0; ni < 2; ni++)
                acc[mi][ni] = __builtin_amdgcn_mfma_f32_16x16x32_bf16(af[mi], bf[ni], acc[mi][ni], 0, 0, 0);
    }

    const long bh_ = bh;
#pragma unroll
    for (int mi = 0; mi < 6; mi++) {
        float bias[4];
#pragma unroll
        for (int r = 0; r < 4; r++) bias[r] = b_qkv[h * 96 + mi * 16 + quad * 4 + r];
#pragma unroll
        for (int ni = 0; ni < 2; ni++) {
            const int l = lw + ni * 16 + l15;
            const f32x4 a = acc[mi][ni];
            if (mi < 2) {           // Q: fold QSCALE, transposed [s][d]
                const uint2 u = f2bf_pk4((a[0] + bias[0]) * QSCALE, (a[1] + bias[1]) * QSCALE,
                                         (a[2] + bias[2]) * QSCALE, (a[3] + bias[3]) * QSCALE);
                *(uint2*)(qT + (bh_ * 1024 + l) * 32 + mi * 16 + quad * 4) = u;
            } else if (mi < 4) {    // K: transposed [t][d]
                const uint2 u = f2bf_pk4(a[0] + bias[0], a[1] + bias[1],
                                         a[2] + bias[2], a[3] + bias[3]);
                *(uint2*)(kT + (bh_ * 1024 + l) * 32 + (mi - 2) * 16 + quad * 4) = u;
            } else {                // V: natural [d][t]
#pragma unroll
                for (int r = 0; r < 4; r++)
                    vN[(bh_ * 32 + (mi - 4) * 16 + quad * 4 + r) * 1024 + l] = f2bf(a[r] + bias[r]);
            }
        }
    }
}

// ---------------------------------------------------------------------------
// Attention R6: occupancy play. Wave = 16 s; iterate 64 t per loop ->
// 4 QK chains + 2 PV chains per wave-iter. Grid (bh=128 -> XCD=h, sblk=16)
// = 2048 blocks = 8 blocks/CU; LDS 10 KB/block; launch_bounds(256,8) caps
// VGPR at 64 -> target 8 waves/SIMD (2x R5's latency hiding).
// ---------------------------------------------------------------------------
__global__ __launch_bounds__(256, 8) void attn_kernel6(
    const u16t* __restrict__ qT, const u16t* __restrict__ kT,
    const u16t* __restrict__ vN, u16t* __restrict__ zT)
{
    __shared__ __align__(16) u16t Ps[4][2][16][40];   // [wv][tt][s-row][32t+pad]

    const int bh = blockIdx.x;
    const int b = bh >> 3, h = bh & 7;
    const int sblk = blockIdx.y * 64;
    const int tid = threadIdx.x, lane = tid & 63, wv = tid >> 6;
    const int l15 = lane & 15, quad = lane >> 4;

    const int s = sblk + wv * 16 + l15;
    const bf16x8 qf = *(const bf16x8*)(qT + ((long)bh * 1024 + s) * 32 + quad * 8);

    const u16t* kp = kT + (long)bh * 1024 * 32 + l15 * 32 + quad * 8;
    const u16t* vp = vN + (long)bh * 32 * 1024 + l15 * 1024 + quad * 8;

    f32x4 zacc[2] = {(f32x4)0.f, (f32x4)0.f};   // [dt]
    f32x4 lacc = (f32x4)0.f;

    for (int t0 = 0; t0 < L_; t0 += 64) {
        // phase 1: 4 independent QK chains (load -> MFMA -> exp2 -> pack -> ds_write)
#pragma unroll
        for (int tg = 0; tg < 4; tg++) {
            const bf16x8 kf = *(const bf16x8*)(kp + (t0 + tg * 16) * 32);
            const f32x4 sv = __builtin_amdgcn_mfma_f32_16x16x32_bf16(kf, qf, (f32x4)0.f, 0, 0, 0);
            f32x4 ev;
#pragma unroll
            for (int i = 0; i < 4; i++) ev[i] = __builtin_amdgcn_exp2f(sv[i]);
            lacc += ev;
            uint2 u;
            u.x = trunc_pk(ev[0], ev[1]);
            u.y = trunc_pk(ev[2], ev[3]);
            *(uint2*)&Ps[wv][tg >> 1][l15][(tg & 1) * 16 + quad * 4] = u;
        }

        // phase 2: 2 PV chains (ds_read + 2 MFMA each)
#pragma unroll
        for (int tt = 0; tt < 2; tt++) {
            const bf16x8 vf0 = *(const bf16x8*)(vp + t0 + tt * 32);
            const bf16x8 vf1 = *(const bf16x8*)(vp + 16 * 1024 + t0 + tt * 32);
            const bf16x8 pf = *(const bf16x8*)&Ps[wv][tt][l15][quad * 8];
            zacc[0] = __builtin_amdgcn_mfma_f32_16x16x32_bf16(vf0, pf, zacc[0], 0, 0, 0);
            zacc[1] = __builtin_amdgcn_mfma_f32_16x16x32_bf16(vf1, pf, zacc[1], 0, 0, 0);
        }
    }

    float lf = (lacc[0] + lacc[1]) + (lacc[2] + lacc[3]);
    lf += __shfl_xor(lf, 16);
    lf += __shfl_xor(lf, 32);
    const float rl = 1.f / lf;                   // lane-local: s = l15-based

    u16t* zrow = zT + ((long)b * 1024 + s) * 256 + h * 32;
    const uint2 u0 = f2bf_pk4(zacc[0][0] * rl, zacc[0][1] * rl, zacc[0][2] * rl, zacc[0][3] * rl);
    *(uint2*)(zrow + quad * 4) = u0;
    const uint2 u1 = f2bf_pk4(zacc[1][0] * rl, zacc[1][1] * rl, zacc[1][2] * rl, zacc[1][3] * rl);
    *(uint2*)(zrow + 16 + quad * 4) = u1;
}

// ---------------------------------------------------------------------------
// Fused output GEMM: out = w_o @ z + w_res @ x + biases. 1024 blocks (4/CU).
// Block = 64 o x 32 l; wave = 32 o x 16 l; K=384 fully unrolled.
// ---------------------------------------------------------------------------
__global__ __launch_bounds__(256) void out_gemm_kernel(
    const u16t* __restrict__ wob, const u16t* __restrict__ wrb,
    const u16t* __restrict__ zT, const u16t* __restrict__ xbT,
    const float* __restrict__ b_o, const float* __restrict__ b_res,
    float* __restrict__ out)
{
    const int lblk = blockIdx.x * 32, oblk = blockIdx.y * 64, b = blockIdx.z;
    const int tid = threadIdx.x, lane = tid & 63, wv = tid >> 6;
    const int wm = wv >> 1, wn = wv & 1;
    const int l15 = lane & 15, quad = lane >> 4;
    const int ow = oblk + wm * 32;
    const int lw = lblk + wn * 16;

    f32x4 acc0 = (f32x4)0.f, acc1 = (f32x4)0.f;

    const u16t* zrow = zT + ((long)b * 1024 + lw + l15) * 256;
    const u16t* xrow = xbT + ((long)b * 1024 + lw + l15) * 128;

#pragma unroll
    for (int ks = 0; ks < 8; ks++) {           // z part, K=256
        const int k0 = ks * 32 + quad * 8;
        const bf16x8 af0 = *(const bf16x8*)(wob + (ow + l15) * 256 + k0);
        const bf16x8 af1 = *(const bf16x8*)(wob + (ow + 16 + l15) * 256 + k0);
        const bf16x8 bf  = *(const bf16x8*)(zrow + k0);
        acc0 = __builtin_amdgcn_mfma_f32_16x16x32_bf16(af0, bf, acc0, 0, 0, 0);
        acc1 = __builtin_amdgcn_mfma_f32_16x16x32_bf16(af1, bf, acc1, 0, 0, 0);
    }
#pragma unroll
    for (int ks = 0; ks < 4; ks++) {           // x part, K=128
        const int k0 = ks * 32 + quad * 8;
        const bf16x8 af0 = *(const bf16x8*)(wrb + (ow + l15) * 128 + k0);
        const bf16x8 af1 = *(const bf16x8*)(wrb + (ow + 16 + l15) * 128 + k0);
        const bf16x8 bf  = *(const bf16x8*)(xrow + k0);
        acc0 = __builtin_amdgcn_mfma_f32_16x16x32_bf16(af0, bf, acc0, 0, 0, 0);
        acc1 = __builtin_amdgcn_mfma_f32_16x16x32_bf16(af1, bf, acc1, 0, 0, 0);
    }

    const int lcol = lw + l15;
#pragma unroll
    for (int mi = 0; mi < 2; mi++) {
        const f32x4 a = (mi == 0) ? acc0 : acc1;
#pragma unroll
        for (int r = 0; r < 4; r++) {
            const int o = ow + mi * 16 + quad * 4 + r;
            out[((long)b * 128 + o) * 1024 + lcol] = a[r] + b_o[o] + b_res[o];
        }
    }
}

// ---------------------------------------------------------------------------
extern "C" void kernel_launch(void* const* d_in, const int* in_sizes, int n_in,
                              void* d_out, int out_size, void* d_ws, size_t ws_size,
                              hipStream_t stream)
{
    const float* x     = (const float*)d_in[0];
    const float* w_qkv = (const float*)d_in[1];
    const float* b_qkv = (const float*)d_in[2];
    const float* w_o   = (const float*)d_in[3];
    const float* b_o   = (const float*)d_in[4];
    const float* w_res = (const float*)d_in[5];
    const float* b_res = (const float*)d_in[6];
    float* out = (float*)d_out;

    u16t* xbT = (u16t*)d_ws;                   // [B][1024][128]
    u16t* qT  = xbT + (size_t)2097152;         // [B][H][1024][32]
    u16t* kT  = qT  + (size_t)4194304;         // [B][H][1024][32]
    u16t* vN  = kT  + (size_t)4194304;         // [B][H][32][1024]
    u16t* zT  = vN  + (size_t)4194304;         // [B][1024][256]
    u16t* wqb = zT  + (size_t)4194304;         // [768][128]
    u16t* wob = wqb + (size_t)98304;           // [128][256]
    u16t* wrb = wob + (size_t)32768;           // [128][128]

    prep_kernel<<<dim3(16, 16, 2), 256, 0, stream>>>(x, w_qkv, w_o, w_res, xbT, wqb, wob, wrb);
    qkv_gemm_kernel<<<dim3(8, 128, 1), 256, 0, stream>>>(wqb, xbT, b_qkv, qT, kT, vN);
    attn_kernel6<<<dim3(128, 16, 1), 256, 0, stream>>>(qT, kT, vN, zT);
    out_gemm_kernel<<<dim3(32, 2, 16), 256, 0, stream>>>(wob, wrb, zT, xbT, b_o, b_res, out);
}

// Round 7
// 161.580 us; speedup vs baseline: 1.2563x; 1.2563x over previous
//
#include <hip/hip_runtime.h>

#define B_    16
#define L_    1024
#define H_    8
#define SCALE  0.17677669529663687f              // 1/sqrt(32)
#define QSCALE 0.25510940349191965f              // SCALE * log2(e)  (exp -> exp2)

typedef __attribute__((ext_vector_type(8))) short bf16x8;
typedef __attribute__((ext_vector_type(4))) float f32x4;
typedef unsigned short u16t;

__device__ inline u16t f2bf(float f) {
    unsigned u = __float_as_uint(f);
    u = (u + 0x7FFF + ((u >> 16) & 1)) >> 16;
    return (u16t)u;
}
__device__ inline unsigned f2bf_pk(float a, float b) {
    unsigned ua = __float_as_uint(a);
    unsigned ub = __float_as_uint(b);
    ua = (ua + 0x7FFF + ((ua >> 16) & 1)) >> 16;
    ub = (ub + 0x7FFF + ((ub >> 16) & 1)) >> 16;
    return ua | (ub << 16);
}
__device__ inline uint2 f2bf_pk4(float a, float b, float c, float d) {
    uint2 u; u.x = f2bf_pk(a, b); u.y = f2bf_pk(c, d); return u;
}
// truncating bf16 pack: low16 = hi(f0), high16 = hi(f1) — one v_perm_b32
__device__ inline unsigned trunc_pk(float f0, float f1) {
    return __builtin_amdgcn_perm(__float_as_uint(f1), __float_as_uint(f0), 0x07060302u);
}

// ---------------------------------------------------------------------------
// Prep: z=0 -> transpose+convert x (B,128,1024) fp32 -> xbT (B,1024,128) bf16
//       z=1 -> convert the three weight matrices fp32 -> bf16 (flat copy)
// ---------------------------------------------------------------------------
__global__ __launch_bounds__(256) void prep_kernel(
    const float* __restrict__ x, const float* __restrict__ w_qkv,
    const float* __restrict__ w_o, const float* __restrict__ w_res,
    u16t* __restrict__ xbT, u16t* __restrict__ wqb,
    u16t* __restrict__ wob, u16t* __restrict__ wrb)
{
    const int tid = threadIdx.x;
    if (blockIdx.z == 0) {
        __shared__ u16t T[64][144];
        const int b = blockIdx.y, l0 = blockIdx.x * 64;
#pragma unroll
        for (int i = 0; i < 8; i++) {
            const int c = i * 16 + (tid >> 4);
            const int l = (tid & 15) * 4;
            const float4 v = *(const float4*)(x + ((long)b * 128 + c) * 1024 + l0 + l);
            T[l + 0][c] = f2bf(v.x);
            T[l + 1][c] = f2bf(v.y);
            T[l + 2][c] = f2bf(v.z);
            T[l + 3][c] = f2bf(v.w);
        }
        __syncthreads();
#pragma unroll
        for (int i = 0; i < 4; i++) {
            const int l  = i * 16 + (tid >> 4);
            const int c0 = (tid & 15) * 8;
            *(uint4*)(xbT + ((long)b * 1024 + l0 + l) * 128 + c0) = *(const uint4*)&T[l][c0];
        }
    } else {
        const int idx = blockIdx.y * 16 + blockIdx.x;
        if (idx >= 144) return;
        const int f = idx * 1024 + tid * 4;
        const float* src; u16t* dst; int off;
        if (f < 98304)       { src = w_qkv; dst = wqb; off = f; }
        else if (f < 131072) { src = w_o;   dst = wob; off = f - 98304; }
        else                 { src = w_res; dst = wrb; off = f - 131072; }
        const float4 v = *(const float4*)(src + off);
        *(uint2*)(dst + off) = f2bf_pk4(v.x, v.y, v.z, v.w);
    }
}

// ---------------------------------------------------------------------------
// QKV GEMM: block = (lblk 128, bh). Wave: 96 o x 32 l, K=128.
// 2-stage register ping-pong over the 4 K-steps: next step's 8 fragment
// loads are in flight during the current 12 MFMAs. launch_bounds(256,4)
// -> VGPR cap 128 so both stages stay live.
// ---------------------------------------------------------------------------
__global__ __launch_bounds__(256, 4) void qkv_gemm_kernel(
    const u16t* __restrict__ wqb, const u16t* __restrict__ xbT,
    const float* __restrict__ b_qkv,
    u16t* __restrict__ qT, u16t* __restrict__ kT, u16t* __restrict__ vN)
{
    const int lblk = blockIdx.x * 128;
    const int bh = blockIdx.y;
    const int b = bh >> 3, h = bh & 7;
    const int tid = threadIdx.x, lane = tid & 63, wv = tid >> 6;
    const int l15 = lane & 15, quad = lane >> 4;
    const int lw = lblk + wv * 32;

    f32x4 acc[6][2];
#pragma unroll
    for (int mi = 0; mi < 6; mi++)
#pragma unroll
        for (int ni = 0; ni < 2; ni++) acc[mi][ni] = (f32x4)0.f;

    const u16t* wrow = wqb + (long)h * 96 * 128 + l15 * 128 + quad * 8;
    const u16t* xr0  = xbT + ((long)b * 1024 + lw + l15) * 128 + quad * 8;
    const u16t* xr1  = xr0 + 16 * 128;

    bf16x8 af[2][6], bf[2][2];
#pragma unroll
    for (int mi = 0; mi < 6; mi++) af[0][mi] = *(const bf16x8*)(wrow + mi * 16 * 128);
    bf[0][0] = *(const bf16x8*)(xr0);
    bf[0][1] = *(const bf16x8*)(xr1);

#pragma unroll
    for (int ks = 0; ks < 4; ks++) {
        const int cur = ks & 1, nxt = cur ^ 1;
        if (ks < 3) {
            const int k0 = (ks + 1) * 32;
#pragma unroll
            for (int mi = 0; mi < 6; mi++) af[nxt][mi] = *(const bf16x8*)(wrow + mi * 16 * 128 + k0);
            bf[nxt][0] = *(const bf16x8*)(xr0 + k0);
            bf[nxt][1] = *(const bf16x8*)(xr1 + k0);
        }
#pragma unroll
        for (int mi = 0; mi < 6; mi++)
#pragma unroll
            for (int ni = 0; ni < 2; ni++)
                acc[mi][ni] = __builtin_amdgcn_mfma_f32_16x16x32_bf16(af[cur][mi], bf[cur][ni], acc[mi][ni], 0, 0, 0);
    }

    const long bh_ = bh;
#pragma unroll
    for (int mi = 0; mi < 6; mi++) {
        float bias[4];
#pragma unroll
        for (int r = 0; r < 4; r++) bias[r] = b_qkv[h * 96 + mi * 16 + quad * 4 + r];
#pragma unroll
        for (int ni = 0; ni < 2; ni++) {
            const int l = lw + ni * 16 + l15;
            const f32x4 a = acc[mi][ni];
            if (mi < 2) {           // Q: fold QSCALE, transposed [s][d]
                const uint2 u = f2bf_pk4((a[0] + bias[0]) * QSCALE, (a[1] + bias[1]) * QSCALE,
                                         (a[2] + bias[2]) * QSCALE, (a[3] + bias[3]) * QSCALE);
                *(uint2*)(qT + (bh_ * 1024 + l) * 32 + mi * 16 + quad * 4) = u;
            } else if (mi < 4) {    // K: transposed [t][d]
                const uint2 u = f2bf_pk4(a[0] + bias[0], a[1] + bias[1],
                                         a[2] + bias[2], a[3] + bias[3]);
                *(uint2*)(kT + (bh_ * 1024 + l) * 32 + (mi - 2) * 16 + quad * 4) = u;
            } else {                // V: natural [d][t]
#pragma unroll
                for (int r = 0; r < 4; r++)
                    vN[(bh_ * 32 + (mi - 4) * 16 + quad * 4 + r) * 1024 + l] = f2bf(a[r] + bias[r]);
            }
        }
    }
}

// ---------------------------------------------------------------------------
// Attention R7: R5 shape (wave = 32 s, 64 t/iter, 4 QK + 4 PV chains) +
// register double-buffered K/V prefetch (next iter's 8 loads in flight
// during current iter's compute) + launch_bounds(256,4) so ~112 VGPRs of
// live state actually fit (R5/R6 were compiler-starved at 44/24 VGPRs ->
// serialized L2 loads, ~2000 cyc/iter chains).
// Grid (x=bh -> XCD=h, y=sblk[8]) = 1024 blocks = 4/CU = 4 waves/SIMD.
// ---------------------------------------------------------------------------
__global__ __launch_bounds__(256, 4) void attn_kernel7(
    const u16t* __restrict__ qT, const u16t* __restrict__ kT,
    const u16t* __restrict__ vN, u16t* __restrict__ zT)
{
    __shared__ __align__(16) u16t Ps[4][2][2][16][40];   // [wv][st][tt][s-row][32t+pad]

    const int bh = blockIdx.x;
    const int b = bh >> 3, h = bh & 7;
    const int sblk = blockIdx.y * 128;
    const int tid = threadIdx.x, lane = tid & 63, wv = tid >> 6;
    const int l15 = lane & 15, quad = lane >> 4;

    const int sw = sblk + wv * 32;
    bf16x8 qf[2];
    qf[0] = *(const bf16x8*)(qT + ((long)bh * 1024 + sw + l15) * 32 + quad * 8);
    qf[1] = *(const bf16x8*)(qT + ((long)bh * 1024 + sw + 16 + l15) * 32 + quad * 8);

    const u16t* kp = kT + (long)bh * 1024 * 32 + l15 * 32 + quad * 8;
    const u16t* vp = vN + (long)bh * 32 * 1024 + l15 * 1024 + quad * 8;

    f32x4 zacc[2][2];                // [st][dt]
#pragma unroll
    for (int a = 0; a < 2; a++)
#pragma unroll
        for (int c = 0; c < 2; c++) zacc[a][c] = (f32x4)0.f;
    f32x4 lacc4[2] = {(f32x4)0.f, (f32x4)0.f};

    // prime iteration 0's fragments
    bf16x8 kf[4], vf[4];             // vf[dt*2+tt]
#pragma unroll
    for (int tg = 0; tg < 4; tg++)
        kf[tg] = *(const bf16x8*)(kp + tg * 16 * 32);
#pragma unroll
    for (int dt = 0; dt < 2; dt++)
#pragma unroll
        for (int tt = 0; tt < 2; tt++)
            vf[dt * 2 + tt] = *(const bf16x8*)(vp + dt * 16 * 1024 + tt * 32);

    for (int t0 = 0; t0 < L_; t0 += 64) {
        // prefetch next iteration's 8 fragments (wraps on last iter; discarded)
        const int tn = (t0 + 64) & 1023;
        bf16x8 nk[4], nv[4];
#pragma unroll
        for (int tg = 0; tg < 4; tg++)
            nk[tg] = *(const bf16x8*)(kp + (tn + tg * 16) * 32);
#pragma unroll
        for (int dt = 0; dt < 2; dt++)
#pragma unroll
            for (int tt = 0; tt < 2; tt++)
                nv[dt * 2 + tt] = *(const bf16x8*)(vp + dt * 16 * 1024 + tn + tt * 32);

        // phase 1: 8 independent QK chains (MFMA -> exp2 -> pack -> ds_write)
#pragma unroll
        for (int st = 0; st < 2; st++) {
#pragma unroll
            for (int tg = 0; tg < 4; tg++) {
                const f32x4 sv = __builtin_amdgcn_mfma_f32_16x16x32_bf16(kf[tg], qf[st], (f32x4)0.f, 0, 0, 0);
                f32x4 ev;
#pragma unroll
                for (int i = 0; i < 4; i++) ev[i] = __builtin_amdgcn_exp2f(sv[i]);
                lacc4[st] += ev;
                uint2 u;
                u.x = trunc_pk(ev[0], ev[1]);
                u.y = trunc_pk(ev[2], ev[3]);
                *(uint2*)&Ps[wv][st][tg >> 1][l15][(tg & 1) * 16 + quad * 4] = u;
            }
        }

        // phase 2: 4 P-reads + 8 PV MFMAs
#pragma unroll
        for (int st = 0; st < 2; st++) {
#pragma unroll
            for (int tt = 0; tt < 2; tt++) {
                const bf16x8 pf = *(const bf16x8*)&Ps[wv][st][tt][l15][quad * 8];
                zacc[st][0] = __builtin_amdgcn_mfma_f32_16x16x32_bf16(vf[tt], pf, zacc[st][0], 0, 0, 0);
                zacc[st][1] = __builtin_amdgcn_mfma_f32_16x16x32_bf16(vf[2 + tt], pf, zacc[st][1], 0, 0, 0);
            }
        }

        // rotate buffers
#pragma unroll
        for (int i = 0; i < 4; i++) { kf[i] = nk[i]; vf[i] = nv[i]; }
    }

#pragma unroll
    for (int st = 0; st < 2; st++) {
        float lf = (lacc4[st][0] + lacc4[st][1]) + (lacc4[st][2] + lacc4[st][3]);
        lf += __shfl_xor(lf, 16);
        lf += __shfl_xor(lf, 32);
        const float rl = 1.f / lf;               // lane-local: s = l15-based
        const int s = sblk + wv * 32 + st * 16 + l15;
        u16t* zrow = zT + ((long)b * 1024 + s) * 256 + h * 32;
        const uint2 u0 = f2bf_pk4(zacc[st][0][0] * rl, zacc[st][0][1] * rl,
                                  zacc[st][0][2] * rl, zacc[st][0][3] * rl);
        *(uint2*)(zrow + quad * 4) = u0;
        const uint2 u1 = f2bf_pk4(zacc[st][1][0] * rl, zacc[st][1][1] * rl,
                                  zacc[st][1][2] * rl, zacc[st][1][3] * rl);
        *(uint2*)(zrow + 16 + quad * 4) = u1;
    }
}

// ---------------------------------------------------------------------------
// Fused output GEMM: out = w_o @ z + w_res @ x + biases. Unified 12-step
// K-loop (8 over w_o/z, 4 over w_res/x) with 2-stage register ping-pong.
// 1024 blocks (4/CU); block = 64 o x 32 l; wave = 32 o x 16 l.
// ---------------------------------------------------------------------------
__global__ __launch_bounds__(256, 4) void out_gemm_kernel(
    const u16t* __restrict__ wob, const u16t* __restrict__ wrb,
    const u16t* __restrict__ zT, const u16t* __restrict__ xbT,
    const float* __restrict__ b_o, const float* __restrict__ b_res,
    float* __restrict__ out)
{
    const int lblk = blockIdx.x * 32, oblk = blockIdx.y * 64, b = blockIdx.z;
    const int tid = threadIdx.x, lane = tid & 63, wv = tid >> 6;
    const int wm = wv >> 1, wn = wv & 1;
    const int l15 = lane & 15, quad = lane >> 4;
    const int ow = oblk + wm * 32;
    const int lw = lblk + wn * 16;

    f32x4 acc0 = (f32x4)0.f, acc1 = (f32x4)0.f;

    const u16t* zrow = zT + ((long)b * 1024 + lw + l15) * 256 + quad * 8;
    const u16t* xrow = xbT + ((long)b * 1024 + lw + l15) * 128 + quad * 8;
    const u16t* wo0 = wob + (ow + l15) * 256 + quad * 8;
    const u16t* wo1 = wob + (ow + 16 + l15) * 256 + quad * 8;
    const u16t* wr0 = wrb + (ow + l15) * 128 + quad * 8;
    const u16t* wr1 = wrb + (ow + 16 + l15) * 128 + quad * 8;

    bf16x8 af0[2], af1[2], bf[2];
    af0[0] = *(const bf16x8*)(wo0);
    af1[0] = *(const bf16x8*)(wo1);
    bf[0]  = *(const bf16x8*)(zrow);

#pragma unroll
    for (int ks = 0; ks < 12; ks++) {
        const int cur = ks & 1, nxt = cur ^ 1;
        if (ks < 11) {
            const int kn = ks + 1;
            if (kn < 8) {
                af0[nxt] = *(const bf16x8*)(wo0 + kn * 32);
                af1[nxt] = *(const bf16x8*)(wo1 + kn * 32);
                bf[nxt]  = *(const bf16x8*)(zrow + kn * 32);
            } else {
                af0[nxt] = *(const bf16x8*)(wr0 + (kn - 8) * 32);
                af1[nxt] = *(const bf16x8*)(wr1 + (kn - 8) * 32);
                bf[nxt]  = *(const bf16x8*)(xrow + (kn - 8) * 32);
            }
        }
        acc0 = __builtin_amdgcn_mfma_f32_16x16x32_bf16(af0[cur], bf[cur], acc0, 0, 0, 0);
        acc1 = __builtin_amdgcn_mfma_f32_16x16x32_bf16(af1[cur], bf[cur], acc1, 0, 0, 0);
    }

    const int lcol = lw + l15;
#pragma unroll
    for (int mi = 0; mi < 2; mi++) {
        const f32x4 a = (mi == 0) ? acc0 : acc1;
#pragma unroll
        for (int r = 0; r < 4; r++) {
            const int o = ow + mi * 16 + quad * 4 + r;
            out[((long)b * 128 + o) * 1024 + lcol] = a[r] + b_o[o] + b_res[o];
        }
    }
}

// ---------------------------------------------------------------------------
extern "C" void kernel_launch(void* const* d_in, const int* in_sizes, int n_in,
                              void* d_out, int out_size, void* d_ws, size_t ws_size,
                              hipStream_t stream)
{
    const float* x     = (const float*)d_in[0];
    const float* w_qkv = (const float*)d_in[1];
    const float* b_qkv = (const float*)d_in[2];
    const float* w_o   = (const float*)d_in[3];
    const float* b_o   = (const float*)d_in[4];
    const float* w_res = (const float*)d_in[5];
    const float* b_res = (const float*)d_in[6];
    float* out = (float*)d_out;

    u16t* xbT = (u16t*)d_ws;                   // [B][1024][128]
    u16t* qT  = xbT + (size_t)2097152;         // [B][H][1024][32]
    u16t* kT  = qT  + (size_t)4194304;         // [B][H][1024][32]
    u16t* vN  = kT  + (size_t)4194304;         // [B][H][32][1024]
    u16t* zT  = vN  + (size_t)4194304;         // [B][1024][256]
    u16t* wqb = zT  + (size_t)4194304;         // [768][128]
    u16t* wob = wqb + (size_t)98304;           // [128][256]
    u16t* wrb = wob + (size_t)32768;           // [128][128]

    prep_kernel<<<dim3(16, 16, 2), 256, 0, stream>>>(x, w_qkv, w_o, w_res, xbT, wqb, wob, wrb);
    qkv_gemm_kernel<<<dim3(8, 128, 1), 256, 0, stream>>>(wqb, xbT, b_qkv, qT, kT, vN);
    attn_kernel7<<<dim3(128, 8, 1), 256, 0, stream>>>(qT, kT, vN, zT);
    out_gemm_kernel<<<dim3(32, 2, 16), 256, 0, stream>>>(wob, wrb, zT, xbT, b_o, b_res, out);
}

// Round 8
// 136.320 us; speedup vs baseline: 1.4891x; 1.1853x over previous
//
#include <hip/hip_runtime.h>

#define B_    16
#define L_    1024
#define H_    8
#define QSCALE 0.25510940349191965f              // (1/sqrt(32)) * log2(e)  (exp -> exp2)

typedef __attribute__((ext_vector_type(8))) short bf16x8;
typedef __attribute__((ext_vector_type(4))) float f32x4;
typedef unsigned short u16t;

__device__ inline u16t f2bf(float f) {
    unsigned u = __float_as_uint(f);
    u = (u + 0x7FFF + ((u >> 16) & 1)) >> 16;
    return (u16t)u;
}
__device__ inline unsigned f2bf_pk(float a, float b) {
    unsigned ua = __float_as_uint(a);
    unsigned ub = __float_as_uint(b);
    ua = (ua + 0x7FFF + ((ua >> 16) & 1)) >> 16;
    ub = (ub + 0x7FFF + ((ub >> 16) & 1)) >> 16;
    return ua | (ub << 16);
}
__device__ inline uint2 f2bf_pk4(float a, float b, float c, float d) {
    uint2 u; u.x = f2bf_pk(a, b); u.y = f2bf_pk(c, d); return u;
}
// truncating bf16 pack: low16 = hi(f0), high16 = hi(f1) — one v_perm_b32
__device__ inline unsigned trunc_pk(float f0, float f1) {
    return __builtin_amdgcn_perm(__float_as_uint(f1), __float_as_uint(f0), 0x07060302u);
}
// async global->LDS DMA, 16B per lane (global_load_lds_dwordx4)
__device__ inline void async16(const u16t* g, u16t* l) {
    __builtin_amdgcn_global_load_lds(
        (const __attribute__((address_space(1))) unsigned int*)g,
        (__attribute__((address_space(3))) unsigned int*)l, 16, 0, 0);
}

// ---------------------------------------------------------------------------
// Prep: z=0 -> transpose+convert x (B,128,1024) fp32 -> xbT (B,1024,128) bf16
//       z=1 -> convert the three weight matrices fp32 -> bf16 (flat copy)
// ---------------------------------------------------------------------------
__global__ __launch_bounds__(256) void prep_kernel(
    const float* __restrict__ x, const float* __restrict__ w_qkv,
    const float* __restrict__ w_o, const float* __restrict__ w_res,
    u16t* __restrict__ xbT, u16t* __restrict__ wqb,
    u16t* __restrict__ wob, u16t* __restrict__ wrb)
{
    const int tid = threadIdx.x;
    if (blockIdx.z == 0) {
        __shared__ u16t T[64][144];
        const int b = blockIdx.y, l0 = blockIdx.x * 64;
#pragma unroll
        for (int i = 0; i < 8; i++) {
            const int c = i * 16 + (tid >> 4);
            const int l = (tid & 15) * 4;
            const float4 v = *(const float4*)(x + ((long)b * 128 + c) * 1024 + l0 + l);
            T[l + 0][c] = f2bf(v.x);
            T[l + 1][c] = f2bf(v.y);
            T[l + 2][c] = f2bf(v.z);
            T[l + 3][c] = f2bf(v.w);
        }
        __syncthreads();
#pragma unroll
        for (int i = 0; i < 4; i++) {
            const int l  = i * 16 + (tid >> 4);
            const int c0 = (tid & 15) * 8;
            *(uint4*)(xbT + ((long)b * 1024 + l0 + l) * 128 + c0) = *(const uint4*)&T[l][c0];
        }
    } else {
        const int idx = blockIdx.y * 16 + blockIdx.x;
        if (idx >= 144) return;
        const int f = idx * 1024 + tid * 4;
        const float* src; u16t* dst; int off;
        if (f < 98304)       { src = w_qkv; dst = wqb; off = f; }
        else if (f < 131072) { src = w_o;   dst = wob; off = f - 98304; }
        else                 { src = w_res; dst = wrb; off = f - 131072; }
        const float4 v = *(const float4*)(src + off);
        *(uint2*)(dst + off) = f2bf_pk4(v.x, v.y, v.z, v.w);
    }
}

// ---------------------------------------------------------------------------
// QKV GEMM R8: head's weight tile (96x128) staged once into LDS (padded rows,
// +8 halves -> ~2-way reads); all 8 x-fragments preloaded to registers before
// the K-loop (no rotation -> nothing for the scheduler to sink). 48 MFMAs fed
// by ds_read (fine-grained lgkmcnt).
// Epilogue writes: Q -> qT[s][d] (QSCALE folded); K -> kF swizzled
// [chunk][qd][t][8]; V -> vF swizzled [chunk][tq][d][8] — these layouts make
// the attention kernel's lane-linear LDS DMA image fragment-read conflict-free.
// ---------------------------------------------------------------------------
__global__ __launch_bounds__(256) void qkv_gemm_kernel(
    const u16t* __restrict__ wqb, const u16t* __restrict__ xbT,
    const float* __restrict__ b_qkv,
    u16t* __restrict__ qT, u16t* __restrict__ kF, u16t* __restrict__ vF)
{
    __shared__ __align__(16) u16t Ws[96 * 136];   // row stride 136 halves

    const int lblk = blockIdx.x * 128;
    const int bh = blockIdx.y;
    const int b = bh >> 3, h = bh & 7;
    const int tid = threadIdx.x, lane = tid & 63, wv = tid >> 6;
    const int l15 = lane & 15, quad = lane >> 4;
    const int lw = lblk + wv * 32;

    // stage weights: 96x128 halves = 1536 8-half groups; 6 per thread
    {
        const u16t* wsrc = wqb + (long)h * 96 * 128;
#pragma unroll
        for (int i = 0; i < 6; i++) {
            const int g = tid + i * 256;
            const int row = g >> 4, col = g & 15;
            const uint4 w = *(const uint4*)(wsrc + g * 8);
            *(uint4*)&Ws[row * 136 + col * 8] = w;
        }
    }

    // preload all x fragments (8 x b128, no reuse-rotation)
    bf16x8 bfr[4][2];
    {
        const u16t* xr0 = xbT + ((long)b * 1024 + lw + l15) * 128 + quad * 8;
        const u16t* xr1 = xr0 + 16 * 128;
#pragma unroll
        for (int ks = 0; ks < 4; ks++) {
            bfr[ks][0] = *(const bf16x8*)(xr0 + ks * 32);
            bfr[ks][1] = *(const bf16x8*)(xr1 + ks * 32);
        }
    }
    __syncthreads();

    f32x4 acc[6][2];
#pragma unroll
    for (int mi = 0; mi < 6; mi++)
#pragma unroll
        for (int ni = 0; ni < 2; ni++) acc[mi][ni] = (f32x4)0.f;

#pragma unroll
    for (int ks = 0; ks < 4; ks++) {
#pragma unroll
        for (int mi = 0; mi < 6; mi++) {
            const bf16x8 af = *(const bf16x8*)&Ws[(mi * 16 + l15) * 136 + ks * 32 + quad * 8];
            acc[mi][0] = __builtin_amdgcn_mfma_f32_16x16x32_bf16(af, bfr[ks][0], acc[mi][0], 0, 0, 0);
            acc[mi][1] = __builtin_amdgcn_mfma_f32_16x16x32_bf16(af, bfr[ks][1], acc[mi][1], 0, 0, 0);
        }
    }

    const long bh_ = bh;
#pragma unroll
    for (int mi = 0; mi < 6; mi++) {
        float bias[4];
#pragma unroll
        for (int r = 0; r < 4; r++) bias[r] = b_qkv[h * 96 + mi * 16 + quad * 4 + r];
#pragma unroll
        for (int ni = 0; ni < 2; ni++) {
            const int l = lw + ni * 16 + l15;
            const f32x4 a = acc[mi][ni];
            if (mi < 2) {           // Q: fold QSCALE, transposed [s][d]
                const uint2 u = f2bf_pk4((a[0] + bias[0]) * QSCALE, (a[1] + bias[1]) * QSCALE,
                                         (a[2] + bias[2]) * QSCALE, (a[3] + bias[3]) * QSCALE);
                *(uint2*)(qT + (bh_ * 1024 + l) * 32 + mi * 16 + quad * 4) = u;
            } else if (mi < 4) {    // K -> kF [chunk c][qd][tl][8j], d = qd*8+j
                const int t = l, c = t >> 6, tl = t & 63;
                const int qd = (mi - 2) * 2 + (quad >> 1);
                const uint2 u = f2bf_pk4(a[0] + bias[0], a[1] + bias[1],
                                         a[2] + bias[2], a[3] + bias[3]);
                *(uint2*)(kF + (bh_ * 16 + c) * 2048 + qd * 512 + tl * 8 + (quad & 1) * 4) = u;
            } else {                // V -> vF [chunk c][tq][d][8j], t = tq*8+j
                const int t = l, c = t >> 6, tq = (t >> 3) & 7, j = t & 7;
                u16t* vb = vF + (bh_ * 16 + c) * 2048 + tq * 256 + j;
#pragma unroll
                for (int r = 0; r < 4; r++)
                    vb[((mi - 4) * 16 + quad * 4 + r) * 8] = f2bf(a[r] + bias[r]);
            }
        }
    }
}

// ---------------------------------------------------------------------------
// Attention R8 (m97 structure): double-buffered LDS K/V chunks (64 t = 4 KB
// each) staged via global_load_lds (16B/lane, exactly one issue per buffer
// per thread). DMA issued right after the top-of-loop barrier, drained at
// the NEXT barrier -> one full compute phase of latency hiding that the
// compiler cannot undo. kF/vF global layouts are pre-swizzled so the
// lane-linear LDS image gives 2-way (free) fragment ds_read_b128s.
// Wave = 32 s, 64 t/iter (4 QK + 4 PV chains). Grid (x=bh -> XCD=h, y=8).
// ---------------------------------------------------------------------------
__global__ __launch_bounds__(256) void attn_kernel8(
    const u16t* __restrict__ qT, const u16t* __restrict__ kF,
    const u16t* __restrict__ vF, u16t* __restrict__ zT)
{
    __shared__ __align__(16) u16t Ks[2][2048];
    __shared__ __align__(16) u16t Vs[2][2048];
    __shared__ __align__(16) u16t Ps[4][2][2][16][40];   // [wv][st][tt][s][32t+pad]

    const int bh = blockIdx.x;
    const int b = bh >> 3, h = bh & 7;
    const int sblk = blockIdx.y * 128;
    const int tid = threadIdx.x, lane = tid & 63, wv = tid >> 6;
    const int l15 = lane & 15, quad = lane >> 4;

    const int sw = sblk + wv * 32;
    bf16x8 qf[2];
    qf[0] = *(const bf16x8*)(qT + ((long)bh * 1024 + sw + l15) * 32 + quad * 8);
    qf[1] = *(const bf16x8*)(qT + ((long)bh * 1024 + sw + 16 + l15) * 32 + quad * 8);

    const u16t* kg = kF + (long)bh * 32768 + tid * 8;
    const u16t* vg = vF + (long)bh * 32768 + tid * 8;

    // prime chunk 0
    async16(kg, &Ks[0][tid * 8]);
    async16(vg, &Vs[0][tid * 8]);

    f32x4 zacc[2][2];                // [st][dt]
#pragma unroll
    for (int a = 0; a < 2; a++)
#pragma unroll
        for (int c = 0; c < 2; c++) zacc[a][c] = (f32x4)0.f;
    f32x4 lacc4[2] = {(f32x4)0.f, (f32x4)0.f};

    for (int c = 0; c < 16; ++c) {
        const int buf = c & 1;
        __syncthreads();                     // buf[c] DMA drained; prev compute done
        if (c < 15) {                        // stage next chunk; drains at NEXT barrier
            async16(kg + (c + 1) * 2048, &Ks[buf ^ 1][tid * 8]);
            async16(vg + (c + 1) * 2048, &Vs[buf ^ 1][tid * 8]);
        }

        // K fragments: [qd=quad][tl=tg*16+l15][8] -> banks 4*l15 mod 32 (2-way)
        bf16x8 kf[4];
#pragma unroll
        for (int tg = 0; tg < 4; tg++)
            kf[tg] = *(const bf16x8*)&Ks[buf][quad * 512 + (tg * 16 + l15) * 8];

        // phase 1: 8 independent QK chains (MFMA -> exp2 -> pack -> ds_write)
#pragma unroll
        for (int st = 0; st < 2; st++) {
#pragma unroll
            for (int tg = 0; tg < 4; tg++) {
                const f32x4 sv = __builtin_amdgcn_mfma_f32_16x16x32_bf16(kf[tg], qf[st], (f32x4)0.f, 0, 0, 0);
                f32x4 ev;
#pragma unroll
                for (int i = 0; i < 4; i++) ev[i] = __builtin_amdgcn_exp2f(sv[i]);
                lacc4[st] += ev;
                uint2 u;
                u.x = trunc_pk(ev[0], ev[1]);
                u.y = trunc_pk(ev[2], ev[3]);
                *(uint2*)&Ps[wv][st][tg >> 1][l15][(tg & 1) * 16 + quad * 4] = u;
            }
        }

        // phase 2: P reads + V fragments + 8 PV MFMAs
#pragma unroll
        for (int st = 0; st < 2; st++) {
#pragma unroll
            for (int tt = 0; tt < 2; tt++) {
                const bf16x8 pf  = *(const bf16x8*)&Ps[wv][st][tt][l15][quad * 8];
                const bf16x8 vf0 = *(const bf16x8*)&Vs[buf][(tt * 4 + quad) * 256 + l15 * 8];
                const bf16x8 vf1 = *(const bf16x8*)&Vs[buf][(tt * 4 + quad) * 256 + (16 + l15) * 8];
                zacc[st][0] = __builtin_amdgcn_mfma_f32_16x16x32_bf16(vf0, pf, zacc[st][0], 0, 0, 0);
                zacc[st][1] = __builtin_amdgcn_mfma_f32_16x16x32_bf16(vf1, pf, zacc[st][1], 0, 0, 0);
            }
        }
    }

#pragma unroll
    for (int st = 0; st < 2; st++) {
        float lf = (lacc4[st][0] + lacc4[st][1]) + (lacc4[st][2] + lacc4[st][3]);
        lf += __shfl_xor(lf, 16);
        lf += __shfl_xor(lf, 32);
        const float rl = 1.f / lf;               // lane-local: s = l15-based
        const int s = sblk + wv * 32 + st * 16 + l15;
        u16t* zrow = zT + ((long)b * 1024 + s) * 256 + h * 32;
        const uint2 u0 = f2bf_pk4(zacc[st][0][0] * rl, zacc[st][0][1] * rl,
                                  zacc[st][0][2] * rl, zacc[st][0][3] * rl);
        *(uint2*)(zrow + quad * 4) = u0;
        const uint2 u1 = f2bf_pk4(zacc[st][1][0] * rl, zacc[st][1][1] * rl,
                                  zacc[st][1][2] * rl, zacc[st][1][3] * rl);
        *(uint2*)(zrow + 16 + quad * 4) = u1;
    }
}

// ---------------------------------------------------------------------------
// Fused output GEMM: out = w_o @ z + w_res @ x + biases. Unified 12-step
// K-loop with 2-stage register ping-pong. 1024 blocks (4/CU);
// block = 64 o x 32 l; wave = 32 o x 16 l.
// ---------------------------------------------------------------------------
__global__ __launch_bounds__(256, 4) void out_gemm_kernel(
    const u16t* __restrict__ wob, const u16t* __restrict__ wrb,
    const u16t* __restrict__ zT, const u16t* __restrict__ xbT,
    const float* __restrict__ b_o, const float* __restrict__ b_res,
    float* __restrict__ out)
{
    const int lblk = blockIdx.x * 32, oblk = blockIdx.y * 64, b = blockIdx.z;
    const int tid = threadIdx.x, lane = tid & 63, wv = tid >> 6;
    const int wm = wv >> 1, wn = wv & 1;
    const int l15 = lane & 15, quad = lane >> 4;
    const int ow = oblk + wm * 32;
    const int lw = lblk + wn * 16;

    f32x4 acc0 = (f32x4)0.f, acc1 = (f32x4)0.f;

    const u16t* zrow = zT + ((long)b * 1024 + lw + l15) * 256 + quad * 8;
    const u16t* xrow = xbT + ((long)b * 1024 + lw + l15) * 128 + quad * 8;
    const u16t* wo0 = wob + (ow + l15) * 256 + quad * 8;
    const u16t* wo1 = wob + (ow + 16 + l15) * 256 + quad * 8;
    const u16t* wr0 = wrb + (ow + l15) * 128 + quad * 8;
    const u16t* wr1 = wrb + (ow + 16 + l15) * 128 + quad * 8;

    bf16x8 af0[2], af1[2], bf[2];
    af0[0] = *(const bf16x8*)(wo0);
    af1[0] = *(const bf16x8*)(wo1);
    bf[0]  = *(const bf16x8*)(zrow);

#pragma unroll
    for (int ks = 0; ks < 12; ks++) {
        const int cur = ks & 1, nxt = cur ^ 1;
        if (ks < 11) {
            const int kn = ks + 1;
            if (kn < 8) {
                af0[nxt] = *(const bf16x8*)(wo0 + kn * 32);
                af1[nxt] = *(const bf16x8*)(wo1 + kn * 32);
                bf[nxt]  = *(const bf16x8*)(zrow + kn * 32);
            } else {
                af0[nxt] = *(const bf16x8*)(wr0 + (kn - 8) * 32);
                af1[nxt] = *(const bf16x8*)(wr1 + (kn - 8) * 32);
                bf[nxt]  = *(const bf16x8*)(xrow + (kn - 8) * 32);
            }
        }
        acc0 = __builtin_amdgcn_mfma_f32_16x16x32_bf16(af0[cur], bf[cur], acc0, 0, 0, 0);
        acc1 = __builtin_amdgcn_mfma_f32_16x16x32_bf16(af1[cur], bf[cur], acc1, 0, 0, 0);
    }

    const int lcol = lw + l15;
#pragma unroll
    for (int mi = 0; mi < 2; mi++) {
        const f32x4 a = (mi == 0) ? acc0 : acc1;
#pragma unroll
        for (int r = 0; r < 4; r++) {
            const int o = ow + mi * 16 + quad * 4 + r;
            out[((long)b * 128 + o) * 1024 + lcol] = a[r] + b_o[o] + b_res[o];
        }
    }
}

// ---------------------------------------------------------------------------
extern "C" void kernel_launch(void* const* d_in, const int* in_sizes, int n_in,
                              void* d_out, int out_size, void* d_ws, size_t ws_size,
                              hipStream_t stream)
{
    const float* x     = (const float*)d_in[0];
    const float* w_qkv = (const float*)d_in[1];
    const float* b_qkv = (const float*)d_in[2];
    const float* w_o   = (const float*)d_in[3];
    const float* b_o   = (const float*)d_in[4];
    const float* w_res = (const float*)d_in[5];
    const float* b_res = (const float*)d_in[6];
    float* out = (float*)d_out;

    u16t* xbT = (u16t*)d_ws;                   // [B][1024][128]
    u16t* qT  = xbT + (size_t)2097152;         // [B][H][1024][32]
    u16t* kF  = qT  + (size_t)4194304;         // [B*H][16 chunks][2048] swizzled
    u16t* vF  = kF  + (size_t)4194304;         // [B*H][16 chunks][2048] swizzled
    u16t* zT  = vF  + (size_t)4194304;         // [B][1024][256]
    u16t* wqb = zT  + (size_t)4194304;         // [768][128]
    u16t* wob = wqb + (size_t)98304;           // [128][256]
    u16t* wrb = wob + (size_t)32768;           // [128][128]

    prep_kernel<<<dim3(16, 16, 2), 256, 0, stream>>>(x, w_qkv, w_o, w_res, xbT, wqb, wob, wrb);
    qkv_gemm_kernel<<<dim3(8, 128, 1), 256, 0, stream>>>(wqb, xbT, b_qkv, qT, kF, vF);
    attn_kernel8<<<dim3(128, 8, 1), 256, 0, stream>>>(qT, kF, vF, zT);
    out_gemm_kernel<<<dim3(32, 2, 16), 256, 0, stream>>>(wob, wrb, zT, xbT, b_o, b_res, out);
}

// Round 9
// 126.996 us; speedup vs baseline: 1.5984x; 1.0734x over previous
//
#include <hip/hip_runtime.h>

#define B_    16
#define L_    1024
#define H_    8
#define QSCALE 0.25510940349191965f              // (1/sqrt(32)) * log2(e)  (exp -> exp2)

typedef __attribute__((ext_vector_type(8))) short bf16x8;
typedef __attribute__((ext_vector_type(4))) float f32x4;
typedef unsigned short u16t;

__device__ inline u16t f2bf(float f) {
    unsigned u = __float_as_uint(f);
    u = (u + 0x7FFF + ((u >> 16) & 1)) >> 16;
    return (u16t)u;
}
__device__ inline unsigned f2bf_pk(float a, float b) {
    unsigned ua = __float_as_uint(a);
    unsigned ub = __float_as_uint(b);
    ua = (ua + 0x7FFF + ((ua >> 16) & 1)) >> 16;
    ub = (ub + 0x7FFF + ((ub >> 16) & 1)) >> 16;
    return ua | (ub << 16);
}
__device__ inline uint2 f2bf_pk4(float a, float b, float c, float d) {
    uint2 u; u.x = f2bf_pk(a, b); u.y = f2bf_pk(c, d); return u;
}
// truncating bf16 pack: low16 = hi(f0), high16 = hi(f1) — one v_perm_b32
__device__ inline unsigned trunc_pk(float f0, float f1) {
    return __builtin_amdgcn_perm(__float_as_uint(f1), __float_as_uint(f0), 0x07060302u);
}
// async global->LDS DMA, 16B per lane (global_load_lds_dwordx4)
__device__ inline void async16(const u16t* g, u16t* l) {
    __builtin_amdgcn_global_load_lds(
        (const __attribute__((address_space(1))) unsigned int*)g,
        (__attribute__((address_space(3))) unsigned int*)l, 16, 0, 0);
}

// ---------------------------------------------------------------------------
// Prep (transpose only): x (B,128,1024) fp32 -> xbT (B,1024,128) bf16
// ---------------------------------------------------------------------------
__global__ __launch_bounds__(256) void prep_kernel(
    const float* __restrict__ x, u16t* __restrict__ xbT)
{
    __shared__ u16t T[64][144];
    const int tid = threadIdx.x;
    const int b = blockIdx.y, l0 = blockIdx.x * 64;
#pragma unroll
    for (int i = 0; i < 8; i++) {
        const int c = i * 16 + (tid >> 4);
        const int l = (tid & 15) * 4;
        const float4 v = *(const float4*)(x + ((long)b * 128 + c) * 1024 + l0 + l);
        T[l + 0][c] = f2bf(v.x);
        T[l + 1][c] = f2bf(v.y);
        T[l + 2][c] = f2bf(v.z);
        T[l + 3][c] = f2bf(v.w);
    }
    __syncthreads();
#pragma unroll
    for (int i = 0; i < 4; i++) {
        const int l  = i * 16 + (tid >> 4);
        const int c0 = (tid & 15) * 8;
        *(uint4*)(xbT + ((long)b * 1024 + l0 + l) * 128 + c0) = *(const uint4*)&T[l][c0];
    }
}

// ---------------------------------------------------------------------------
// QKV GEMM R9: stage the head's fp32 weights -> LDS bf16 directly (no
// separate convert kernel); preload all 8 x-fragments; 48 ds_read-fed MFMAs.
// Epilogue: Q -> qT[s][d] (QSCALE folded); K -> kF / V -> vF swizzled so the
// attention kernel's lane-linear LDS DMA image is fragment-read conflict-free.
// ---------------------------------------------------------------------------
__global__ __launch_bounds__(256) void qkv_gemm_kernel(
    const float* __restrict__ w_qkv, const u16t* __restrict__ xbT,
    const float* __restrict__ b_qkv,
    u16t* __restrict__ qT, u16t* __restrict__ kF, u16t* __restrict__ vF)
{
    __shared__ __align__(16) u16t Ws[96 * 136];   // row stride 136 halves

    const int lblk = blockIdx.x * 128;
    const int bh = blockIdx.y;
    const int b = bh >> 3, h = bh & 7;
    const int tid = threadIdx.x, lane = tid & 63, wv = tid >> 6;
    const int l15 = lane & 15, quad = lane >> 4;
    const int lw = lblk + wv * 32;

    // stage + convert weights: 96x128 fp32 = 12288 floats, 12 float4/thread
    {
        const float* wsrc = w_qkv + (long)h * 96 * 128;
#pragma unroll
        for (int it = 0; it < 12; it++) {
            const int g = tid * 4 + it * 1024;
            const int row = g >> 7, col = g & 127;
            const float4 w = *(const float4*)(wsrc + g);
            *(uint2*)&Ws[row * 136 + col] = f2bf_pk4(w.x, w.y, w.z, w.w);
        }
    }

    // preload all x fragments (8 x b128, no reuse-rotation)
    bf16x8 bfr[4][2];
    {
        const u16t* xr0 = xbT + ((long)b * 1024 + lw + l15) * 128 + quad * 8;
        const u16t* xr1 = xr0 + 16 * 128;
#pragma unroll
        for (int ks = 0; ks < 4; ks++) {
            bfr[ks][0] = *(const bf16x8*)(xr0 + ks * 32);
            bfr[ks][1] = *(const bf16x8*)(xr1 + ks * 32);
        }
    }
    __syncthreads();

    f32x4 acc[6][2];
#pragma unroll
    for (int mi = 0; mi < 6; mi++)
#pragma unroll
        for (int ni = 0; ni < 2; ni++) acc[mi][ni] = (f32x4)0.f;

#pragma unroll
    for (int ks = 0; ks < 4; ks++) {
#pragma unroll
        for (int mi = 0; mi < 6; mi++) {
            const bf16x8 af = *(const bf16x8*)&Ws[(mi * 16 + l15) * 136 + ks * 32 + quad * 8];
            acc[mi][0] = __builtin_amdgcn_mfma_f32_16x16x32_bf16(af, bfr[ks][0], acc[mi][0], 0, 0, 0);
            acc[mi][1] = __builtin_amdgcn_mfma_f32_16x16x32_bf16(af, bfr[ks][1], acc[mi][1], 0, 0, 0);
        }
    }

    const long bh_ = bh;
#pragma unroll
    for (int mi = 0; mi < 6; mi++) {
        float bias[4];
#pragma unroll
        for (int r = 0; r < 4; r++) bias[r] = b_qkv[h * 96 + mi * 16 + quad * 4 + r];
#pragma unroll
        for (int ni = 0; ni < 2; ni++) {
            const int l = lw + ni * 16 + l15;
            const f32x4 a = acc[mi][ni];
            if (mi < 2) {           // Q: fold QSCALE, transposed [s][d]
                const uint2 u = f2bf_pk4((a[0] + bias[0]) * QSCALE, (a[1] + bias[1]) * QSCALE,
                                         (a[2] + bias[2]) * QSCALE, (a[3] + bias[3]) * QSCALE);
                *(uint2*)(qT + (bh_ * 1024 + l) * 32 + mi * 16 + quad * 4) = u;
            } else if (mi < 4) {    // K -> kF [chunk c][qd][tl][8j], d = qd*8+j
                const int t = l, c = t >> 6, tl = t & 63;
                const int qd = (mi - 2) * 2 + (quad >> 1);
                const uint2 u = f2bf_pk4(a[0] + bias[0], a[1] + bias[1],
                                         a[2] + bias[2], a[3] + bias[3]);
                *(uint2*)(kF + (bh_ * 16 + c) * 2048 + qd * 512 + tl * 8 + (quad & 1) * 4) = u;
            } else {                // V -> vF [chunk c][tq][d][8j], t = tq*8+j
                const int t = l, c = t >> 6, tq = (t >> 3) & 7, j = t & 7;
                u16t* vb = vF + (bh_ * 16 + c) * 2048 + tq * 256 + j;
#pragma unroll
                for (int r = 0; r < 4; r++)
                    vb[((mi - 4) * 16 + quad * 4 + r) * 8] = f2bf(a[r] + bias[r]);
            }
        }
    }
}

// ---------------------------------------------------------------------------
// Attention R9: 512-thread blocks — 8 waves share one K/V double-buffered
// staging (DMA traffic per CU halves vs R8: 2 blocks/CU x 8 KB/chunk).
// Waves 0-3 DMA the K chunk, waves 4-7 the V chunk (wave-uniform split).
// Wave = 32 s, 64 t/iter (4 QK + 4 PV chains). Grid (x=bh -> XCD=h, y=4).
// ---------------------------------------------------------------------------
__global__ __launch_bounds__(512) void attn_kernel9(
    const u16t* __restrict__ qT, const u16t* __restrict__ kF,
    const u16t* __restrict__ vF, u16t* __restrict__ zT)
{
    __shared__ __align__(16) u16t Ks[2][2048];
    __shared__ __align__(16) u16t Vs[2][2048];
    __shared__ __align__(16) u16t Ps[8][2][2][16][40];   // [wv][st][tt][s][32t+pad]

    const int bh = blockIdx.x;
    const int b = bh >> 3, h = bh & 7;
    const int sblk = blockIdx.y * 256;
    const int tid = threadIdx.x, lane = tid & 63, wv = tid >> 6;
    const int l15 = lane & 15, quad = lane >> 4;

    const int sw = sblk + wv * 32;
    bf16x8 qf[2];
    qf[0] = *(const bf16x8*)(qT + ((long)bh * 1024 + sw + l15) * 32 + quad * 8);
    qf[1] = *(const bf16x8*)(qT + ((long)bh * 1024 + sw + 16 + l15) * 32 + quad * 8);

    const u16t* kg = kF + (long)bh * 32768;
    const u16t* vg = vF + (long)bh * 32768;

    // prime chunk 0 (waves 0-3 -> K, waves 4-7 -> V; 256 lanes x 16 B = 4 KB)
    if (tid < 256) async16(kg + tid * 8, &Ks[0][tid * 8]);
    else           async16(vg + (tid - 256) * 8, &Vs[0][(tid - 256) * 8]);

    f32x4 zacc[2][2];                // [st][dt]
#pragma unroll
    for (int a = 0; a < 2; a++)
#pragma unroll
        for (int c = 0; c < 2; c++) zacc[a][c] = (f32x4)0.f;
    f32x4 lacc4[2] = {(f32x4)0.f, (f32x4)0.f};

    for (int c = 0; c < 16; ++c) {
        const int buf = c & 1;
        __syncthreads();                     // buf[c] DMA drained; prev compute done
        if (c < 15) {                        // stage next chunk; drains at NEXT barrier
            const int o = (c + 1) * 2048;
            if (tid < 256) async16(kg + o + tid * 8, &Ks[buf ^ 1][tid * 8]);
            else           async16(vg + o + (tid - 256) * 8, &Vs[buf ^ 1][(tid - 256) * 8]);
        }

        // K fragments: [qd=quad][tl=tg*16+l15][8] -> banks 4*l15 mod 32 (2-way)
        bf16x8 kf[4];
#pragma unroll
        for (int tg = 0; tg < 4; tg++)
            kf[tg] = *(const bf16x8*)&Ks[buf][quad * 512 + (tg * 16 + l15) * 8];

        // phase 1: 8 independent QK chains (MFMA -> exp2 -> pack -> ds_write)
#pragma unroll
        for (int st = 0; st < 2; st++) {
#pragma unroll
            for (int tg = 0; tg < 4; tg++) {
                const f32x4 sv = __builtin_amdgcn_mfma_f32_16x16x32_bf16(kf[tg], qf[st], (f32x4)0.f, 0, 0, 0);
                f32x4 ev;
#pragma unroll
                for (int i = 0; i < 4; i++) ev[i] = __builtin_amdgcn_exp2f(sv[i]);
                lacc4[st] += ev;
                uint2 u;
                u.x = trunc_pk(ev[0], ev[1]);
                u.y = trunc_pk(ev[2], ev[3]);
                *(uint2*)&Ps[wv][st][tg >> 1][l15][(tg & 1) * 16 + quad * 4] = u;
            }
        }

        // phase 2: P reads + V fragments + 8 PV MFMAs
#pragma unroll
        for (int st = 0; st < 2; st++) {
#pragma unroll
            for (int tt = 0; tt < 2; tt++) {
                const bf16x8 pf  = *(const bf16x8*)&Ps[wv][st][tt][l15][quad * 8];
                const bf16x8 vf0 = *(const bf16x8*)&Vs[buf][(tt * 4 + quad) * 256 + l15 * 8];
                const bf16x8 vf1 = *(const bf16x8*)&Vs[buf][(tt * 4 + quad) * 256 + (16 + l15) * 8];
                zacc[st][0] = __builtin_amdgcn_mfma_f32_16x16x32_bf16(vf0, pf, zacc[st][0], 0, 0, 0);
                zacc[st][1] = __builtin_amdgcn_mfma_f32_16x16x32_bf16(vf1, pf, zacc[st][1], 0, 0, 0);
            }
        }
    }

#pragma unroll
    for (int st = 0; st < 2; st++) {
        float lf = (lacc4[st][0] + lacc4[st][1]) + (lacc4[st][2] + lacc4[st][3]);
        lf += __shfl_xor(lf, 16);
        lf += __shfl_xor(lf, 32);
        const float rl = 1.f / lf;               // lane-local: s = l15-based
        const int s = sblk + wv * 32 + st * 16 + l15;
        u16t* zrow = zT + ((long)b * 1024 + s) * 256 + h * 32;
        const uint2 u0 = f2bf_pk4(zacc[st][0][0] * rl, zacc[st][0][1] * rl,
                                  zacc[st][0][2] * rl, zacc[st][0][3] * rl);
        *(uint2*)(zrow + quad * 4) = u0;
        const uint2 u1 = f2bf_pk4(zacc[st][1][0] * rl, zacc[st][1][1] * rl,
                                  zacc[st][1][2] * rl, zacc[st][1][3] * rl);
        *(uint2*)(zrow + 16 + quad * 4) = u1;
    }
}

// ---------------------------------------------------------------------------
// Fused output GEMM R9: stage fp32 w_o/w_res -> LDS bf16 once; preload all
// 12 B-fragments to registers before the barrier; 12 ds_read-fed MFMAs —
// no global load inside the K-loop (kills the sunk-load serial chain).
// 1024 blocks; block = 64 o x 32 l; wave = 32 o x 16 l.
// ---------------------------------------------------------------------------
__global__ __launch_bounds__(256) void out_gemm_kernel(
    const float* __restrict__ w_o, const float* __restrict__ w_res,
    const u16t* __restrict__ zT, const u16t* __restrict__ xbT,
    const float* __restrict__ b_o, const float* __restrict__ b_res,
    float* __restrict__ out)
{
    __shared__ __align__(16) u16t Wo[64 * 264];   // 64 x 256, stride 264
    __shared__ __align__(16) u16t Wr[64 * 136];   // 64 x 128, stride 136

    const int lblk = blockIdx.x * 32, oblk = blockIdx.y * 64, b = blockIdx.z;
    const int tid = threadIdx.x, lane = tid & 63, wv = tid >> 6;
    const int wm = wv >> 1, wn = wv & 1;
    const int l15 = lane & 15, quad = lane >> 4;
    const int ow = oblk + wm * 32;
    const int lw = lblk + wn * 16;

    // stage + convert weights (w_o: 16384 floats, w_res: 8192 floats)
#pragma unroll
    for (int it = 0; it < 16; it++) {
        const int g = tid * 4 + it * 1024;
        const int row = g >> 8, col = g & 255;
        const float4 w = *(const float4*)(w_o + (long)(oblk + row) * 256 + col);
        *(uint2*)&Wo[row * 264 + col] = f2bf_pk4(w.x, w.y, w.z, w.w);
    }
#pragma unroll
    for (int it = 0; it < 8; it++) {
        const int g = tid * 4 + it * 1024;
        const int row = g >> 7, col = g & 127;
        const float4 w = *(const float4*)(w_res + (long)(oblk + row) * 128 + col);
        *(uint2*)&Wr[row * 136 + col] = f2bf_pk4(w.x, w.y, w.z, w.w);
    }

    // preload all 12 B fragments
    bf16x8 bfz[8], bfx[4];
    {
        const u16t* zrow = zT + ((long)b * 1024 + lw + l15) * 256 + quad * 8;
        const u16t* xrow = xbT + ((long)b * 1024 + lw + l15) * 128 + quad * 8;
#pragma unroll
        for (int ks = 0; ks < 8; ks++) bfz[ks] = *(const bf16x8*)(zrow + ks * 32);
#pragma unroll
        for (int ks = 0; ks < 4; ks++) bfx[ks] = *(const bf16x8*)(xrow + ks * 32);
    }
    __syncthreads();

    f32x4 acc0 = (f32x4)0.f, acc1 = (f32x4)0.f;

#pragma unroll
    for (int ks = 0; ks < 8; ks++) {
        const bf16x8 af0 = *(const bf16x8*)&Wo[(wm * 32 + l15) * 264 + ks * 32 + quad * 8];
        const bf16x8 af1 = *(const bf16x8*)&Wo[(wm * 32 + 16 + l15) * 264 + ks * 32 + quad * 8];
        acc0 = __builtin_amdgcn_mfma_f32_16x16x32_bf16(af0, bfz[ks], acc0, 0, 0, 0);
        acc1 = __builtin_amdgcn_mfma_f32_16x16x32_bf16(af1, bfz[ks], acc1, 0, 0, 0);
    }
#pragma unroll
    for (int ks = 0; ks < 4; ks++) {
        const bf16x8 af0 = *(const bf16x8*)&Wr[(wm * 32 + l15) * 136 + ks * 32 + quad * 8];
        const bf16x8 af1 = *(const bf16x8*)&Wr[(wm * 32 + 16 + l15) * 136 + ks * 32 + quad * 8];
        acc0 = __builtin_amdgcn_mfma_f32_16x16x32_bf16(af0, bfx[ks], acc0, 0, 0, 0);
        acc1 = __builtin_amdgcn_mfma_f32_16x16x32_bf16(af1, bfx[ks], acc1, 0, 0, 0);
    }

    const int lcol = lw + l15;
#pragma unroll
    for (int mi = 0; mi < 2; mi++) {
        const f32x4 a = (mi == 0) ? acc0 : acc1;
#pragma unroll
        for (int r = 0; r < 4; r++) {
            const int o = ow + mi * 16 + quad * 4 + r;
            out[((long)b * 128 + o) * 1024 + lcol] = a[r] + b_o[o] + b_res[o];
        }
    }
}

// ---------------------------------------------------------------------------
extern "C" void kernel_launch(void* const* d_in, const int* in_sizes, int n_in,
                              void* d_out, int out_size, void* d_ws, size_t ws_size,
                              hipStream_t stream)
{
    const float* x     = (const float*)d_in[0];
    const float* w_qkv = (const float*)d_in[1];
    const float* b_qkv = (const float*)d_in[2];
    const float* w_o   = (const float*)d_in[3];
    const float* b_o   = (const float*)d_in[4];
    const float* w_res = (const float*)d_in[5];
    const float* b_res = (const float*)d_in[6];
    float* out = (float*)d_out;

    u16t* xbT = (u16t*)d_ws;                   // [B][1024][128]
    u16t* qT  = xbT + (size_t)2097152;         // [B][H][1024][32]
    u16t* kF  = qT  + (size_t)4194304;         // [B*H][16 chunks][2048] swizzled
    u16t* vF  = kF  + (size_t)4194304;         // [B*H][16 chunks][2048] swizzled
    u16t* zT  = vF  + (size_t)4194304;         // [B][1024][256]

    prep_kernel<<<dim3(16, 16), 256, 0, stream>>>(x, xbT);
    qkv_gemm_kernel<<<dim3(8, 128), 256, 0, stream>>>(w_qkv, xbT, b_qkv, qT, kF, vF);
    attn_kernel9<<<dim3(128, 4), 512, 0, stream>>>(qT, kF, vF, zT);
    out_gemm_kernel<<<dim3(32, 2, 16), 256, 0, stream>>>(w_o, w_res, zT, xbT, b_o, b_res, out);
}